// Round 4
// baseline (849.977 us; speedup 1.0000x reference)
//
#include <hip/hip_runtime.h>

#define NB 64
#define ND 128
#define NT 2048
#define NK 1024
#define NN (NB*NT)            // 131072
#define DTSTRIDE (ND*NT)      // 262144, b-stride in x

typedef __attribute__((ext_vector_type(8))) short bf16x8;
typedef __attribute__((ext_vector_type(4))) float floatx4;

// ---- workspace layout (float index) ----
#define WS_ET    0            // 131072 floats, ET[d][k] fp32 (for out_write gather)
#define WS_SSX   131072       // 131072 floats, |x_n|^2
#define WS_SSE   262144       // 1024 floats,  |e_k|^2
#define WS_DW    263168       // 131072 floats, dw[k][d]
#define WS_CS    394240       // 1024 floats
#define WS_CNT   395264       // 1024 ints, counts
#define WS_IDX   396288       // 131072 ints, argmin indices
#define WS_LOSS  527360       // 1 float
#define WS_OFFS  527364       // 1024 ints
#define WS_CUR   528388       // 1024 ints
#define WS_LIST  529412       // 131072 ints
#define WS_XT    660736       // 16777216 floats, xt[n][d]
#define WS_EB    17437952     // 3 x 131072 ushorts: bf16 e-planes [dchunk 4][k 1024][d 32]

// ---- output layout ----
#define O_OUT 0
#define O_LC  16777216
#define O_LV  16777217
#define O_IDX 16777218
#define O_NE  16908290

// exact truncation split of fp32 into 3 bf16 (bit patterns)
__device__ inline void split1(float v, unsigned short &a, unsigned short &b,
                              unsigned short &c) {
    unsigned int u = __float_as_uint(v);
    a = (unsigned short)(u >> 16);
    float f1 = __uint_as_float(u & 0xffff0000u);
    float r = v - f1;
    unsigned int ur = __float_as_uint(r);
    b = (unsigned short)(ur >> 16);
    float f2 = __uint_as_float(ur & 0xffff0000u);
    float r2 = r - f2;
    c = (unsigned short)(__float_as_uint(r2) >> 16);
}

// pack 2 consecutive elements into one uint per plane
__device__ inline void split2(float va, float vb, unsigned int &p1,
                              unsigned int &p2, unsigned int &p3) {
    unsigned int ua = __float_as_uint(va), ub = __float_as_uint(vb);
    p1 = (ua >> 16) | (ub & 0xffff0000u);
    float fa = __uint_as_float(ua & 0xffff0000u);
    float fb = __uint_as_float(ub & 0xffff0000u);
    float ra = va - fa, rb = vb - fb;
    unsigned int ura = __float_as_uint(ra), urb = __float_as_uint(rb);
    p2 = (ura >> 16) | (urb & 0xffff0000u);
    float f2a = __uint_as_float(ura & 0xffff0000u);
    float f2b = __uint_as_float(urb & 0xffff0000u);
    float r2a = ra - f2a, r2b = rb - f2b;
    p3 = (__float_as_uint(r2a) >> 16) | (__float_as_uint(r2b) & 0xffff0000u);
}

// Kernel 1: ET fp32 [d][k], sse, bf16 e-planes (unchanged).
__global__ void prep_e(const float* __restrict__ emb, float* __restrict__ ET,
                       float* __restrict__ sse, unsigned short* __restrict__ eb1,
                       unsigned short* __restrict__ eb2, unsigned short* __restrict__ eb3) {
    int tid = threadIdx.x;
    int k   = blockIdx.x * 16 + (tid >> 4);
    int l   = tid & 15;
    float ss = 0.f;
    #pragma unroll
    for (int it = 0; it < 2; ++it) {
        int d0 = l * 4 + it * 64;
        float4 v = *(const float4*)(emb + k * ND + d0);
        ET[(d0+0)*NK + k] = v.x;
        ET[(d0+1)*NK + k] = v.y;
        ET[(d0+2)*NK + k] = v.z;
        ET[(d0+3)*NK + k] = v.w;
        ss = fmaf(v.x, v.x, ss); ss = fmaf(v.y, v.y, ss);
        ss = fmaf(v.z, v.z, ss); ss = fmaf(v.w, v.w, ss);
        int dc  = (l >> 3) + it * 2;
        int off = (dc * NK + k) * 32 + (d0 & 31);
        ushort4 a, b, c;
        split1(v.x, a.x, b.x, c.x);
        split1(v.y, a.y, b.y, c.y);
        split1(v.z, a.z, b.z, c.z);
        split1(v.w, a.w, b.w, c.w);
        *(ushort4*)(eb1 + off) = a;
        *(ushort4*)(eb2 + off) = b;
        *(ushort4*)(eb3 + off) = c;
    }
    for (int m = 1; m <= 8; m <<= 1) ss += __shfl_xor(ss, m);
    if (l == 0) sse[k] = ss;
}

// Kernel 2: |x_n|^2 (unchanged — argmin numerics stable).
__global__ void calc_ssx(const float* __restrict__ x, float* __restrict__ ssx) {
    int b = blockIdx.x >> 3;
    int t = ((blockIdx.x & 7) << 8) + threadIdx.x;
    const float* xp = x + b * DTSTRIDE + t;
    float ss = 0.f;
    #pragma unroll 8
    for (int d = 0; d < ND; ++d) { float v = xp[d * NT]; ss = fmaf(v, v, ss); }
    ssx[b * NT + t] = ss;
}

// Kernel 2b: transpose x[B][D][T] -> xt[N][D] (unchanged).
__global__ void transpose_x(const float* __restrict__ x, float* __restrict__ xt) {
    __shared__ float tile[128][33];
    int tid = threadIdx.x;
    int b   = blockIdx.x >> 6;
    int t0  = (blockIdx.x & 63) << 5;
    int tl  = tid & 31;
    int dg  = tid >> 5;
    const float* xp = x + b * DTSTRIDE + t0 + tl;
    #pragma unroll
    for (int p = 0; p < 16; ++p) {
        int d = p * 8 + dg;
        tile[d][tl] = xp[d * NT];
    }
    __syncthreads();
    float* xtp = xt + (size_t)(b * NT + t0) * ND;
    #pragma unroll
    for (int c = 0; c < 4; ++c) {
        int d = c * 32 + (tid & 31);
        #pragma unroll
        for (int p = 0; p < 4; ++p) {
            int tr = p * 8 + (tid >> 5);
            xtp[tr * ND + d] = tile[d][tr];
        }
    }
}

// Kernel 3: barrier-free MFMA distance GEMM + argmin + counts + loss.
// Per wave: A (32 rows x 128 d, 3 bf16 planes) lives in 96 VGPRs, loaded once.
// B frags stream straight from the L2-resident eb planes. No LDS, no barriers.
__launch_bounds__(256, 2)
__global__ void gemm_argmin_mfma(const float* __restrict__ xt,
                                 const unsigned short* __restrict__ eb1,
                                 const unsigned short* __restrict__ eb2,
                                 const unsigned short* __restrict__ eb3,
                                 const float* __restrict__ ssx, const float* __restrict__ sse,
                                 float* __restrict__ out, int* __restrict__ idxi,
                                 int* __restrict__ counts, float* __restrict__ loss) {
    int tid = threadIdx.x;
    int blk = blockIdx.x;
    int b   = blk >> 4;
    int t0  = (blk & 15) << 7;
    int n0  = b * NT + t0;

    int lane = tid & 63;
    int w    = tid >> 6;          // wave id: rows [w*32, w*32+32)
    int c    = lane & 15;
    int q    = lane >> 4;

    // ---- load + split A fragments once: af[dc][i][plane] ----
    bf16x8 af[4][2][3];
    #pragma unroll
    for (int dc = 0; dc < 4; ++dc) {
        #pragma unroll
        for (int i = 0; i < 2; ++i) {
            const float* xp = xt + (size_t)(n0 + w*32 + i*16 + c) * ND + dc*32 + q*8;
            float4 v0 = *(const float4*)(xp + 0);
            float4 v1 = *(const float4*)(xp + 4);
            unsigned int p1[4], p2[4], p3[4];
            split2(v0.x, v0.y, p1[0], p2[0], p3[0]);
            split2(v0.z, v0.w, p1[1], p2[1], p3[1]);
            split2(v1.x, v1.y, p1[2], p2[2], p3[2]);
            split2(v1.z, v1.w, p1[3], p2[3], p3[3]);
            uint4 u;
            u = make_uint4(p1[0], p1[1], p1[2], p1[3]); af[dc][i][0] = *(bf16x8*)&u;
            u = make_uint4(p2[0], p2[1], p2[2], p2[3]); af[dc][i][1] = *(bf16x8*)&u;
            u = make_uint4(p3[0], p3[1], p3[2], p3[3]); af[dc][i][2] = *(bf16x8*)&u;
        }
    }

    float ssxv[8];
    #pragma unroll
    for (int i = 0; i < 2; ++i)
        #pragma unroll
        for (int rr = 0; rr < 4; ++rr)
            ssxv[i*4+rr] = ssx[n0 + w*32 + i*16 + q*4 + rr];

    float bestD[8]; int bestK[8];
    #pragma unroll
    for (int i = 0; i < 8; ++i) { bestD[i] = 3.4e38f; bestK[i] = 0; }

    for (int kt = 0; kt < 8; ++kt) {
        floatx4 acc[2][8];
        #pragma unroll
        for (int i = 0; i < 2; ++i)
            #pragma unroll
            for (int j = 0; j < 8; ++j)
                acc[i][j] = (floatx4){0.f, 0.f, 0.f, 0.f};

        for (int dc = 0; dc < 4; ++dc) {
            int ebase = ((dc << 10) + (kt << 7) + c) * 32 + q * 8;
            #pragma unroll
            for (int j = 0; j < 8; ++j) {
                int eoff = ebase + (j << 4) * 32;
                bf16x8 b1 = *(const bf16x8*)(eb1 + eoff);
                bf16x8 b2 = *(const bf16x8*)(eb2 + eoff);
                bf16x8 b3 = *(const bf16x8*)(eb3 + eoff);
                #pragma unroll
                for (int i = 0; i < 2; ++i) {
                    acc[i][j] = __builtin_amdgcn_mfma_f32_16x16x32_bf16(af[dc][i][0], b1, acc[i][j], 0, 0, 0);
                    acc[i][j] = __builtin_amdgcn_mfma_f32_16x16x32_bf16(af[dc][i][0], b2, acc[i][j], 0, 0, 0);
                    acc[i][j] = __builtin_amdgcn_mfma_f32_16x16x32_bf16(af[dc][i][1], b1, acc[i][j], 0, 0, 0);
                    acc[i][j] = __builtin_amdgcn_mfma_f32_16x16x32_bf16(af[dc][i][1], b2, acc[i][j], 0, 0, 0);
                    acc[i][j] = __builtin_amdgcn_mfma_f32_16x16x32_bf16(af[dc][i][0], b3, acc[i][j], 0, 0, 0);
                    acc[i][j] = __builtin_amdgcn_mfma_f32_16x16x32_bf16(af[dc][i][2], b1, acc[i][j], 0, 0, 0);
                }
            }
        }

        // epilogue for this kt tile (identical numerics to R3)
        #pragma unroll
        for (int j = 0; j < 8; ++j) {
            int   kidx = (kt << 7) + (j << 4) + c;
            float ssev = sse[kidx];
            #pragma unroll
            for (int i = 0; i < 2; ++i) {
                #pragma unroll
                for (int rr = 0; rr < 4; ++rr) {
                    float t1   = ssxv[i*4+rr] + ssev;
                    float dist = fmaf(-2.f, acc[i][j][rr], t1);
                    if (dist < bestD[i*4+rr]) { bestD[i*4+rr] = dist; bestK[i*4+rr] = kidx; }
                }
            }
        }
    }

    // cross-lane argmin over the 16 c-lanes (ties -> smaller k)
    #pragma unroll
    for (int i = 0; i < 8; ++i) {
        float d = bestD[i]; int kk = bestK[i];
        for (int m = 1; m <= 8; m <<= 1) {
            float od = __shfl_xor(d, m);
            int   ok = __shfl_xor(kk, m);
            if (od < d || (od == d && ok < kk)) { d = od; kk = ok; }
        }
        bestD[i] = d; bestK[i] = kk;
    }
    if (c == 0) {
        float ls = 0.f;
        #pragma unroll
        for (int i = 0; i < 2; ++i)
            #pragma unroll
            for (int rr = 0; rr < 4; ++rr) {
                int n = n0 + w*32 + i*16 + q*4 + rr;
                int kk = bestK[i*4+rr];
                out[O_IDX + n] = (float)kk;
                idxi[n] = kk;
                atomicAdd(&counts[kk], 1);
                ls += bestD[i*4+rr];
            }
        atomicAdd(loss, ls);
    }
}

// Kernel 4: straight-through output (unchanged).
__global__ void out_write(const float* __restrict__ x, const float* __restrict__ ET,
                          const int* __restrict__ idxi, float* __restrict__ out) {
    int b = blockIdx.x >> 3;
    int t = ((blockIdx.x & 7) << 8) + threadIdx.x;
    int k = idxi[b * NT + t];
    const float* xp = x + b * DTSTRIDE + t;
    float*       op = out + O_OUT + b * DTSTRIDE + t;
    #pragma unroll 4
    for (int d = 0; d < ND; ++d) {
        float xv = xp[d * NT];
        float q  = ET[d * NK + k];
        op[d * NT] = xv + (q - xv);
    }
}

// Kernel 5: exclusive scan of counts (unchanged).
__global__ void scan_offs(const int* __restrict__ counts, int* __restrict__ offs,
                          int* __restrict__ cur) {
    __shared__ int s[256];
    int tid = threadIdx.x;
    int c[4]; int sum = 0;
    #pragma unroll
    for (int j = 0; j < 4; ++j) { c[j] = counts[tid*4+j]; sum += c[j]; }
    s[tid] = sum; __syncthreads();
    for (int off = 1; off < 256; off <<= 1) {
        int v = (tid >= off) ? s[tid - off] : 0;
        __syncthreads();
        s[tid] += v;
        __syncthreads();
    }
    int base = (tid == 0) ? 0 : s[tid-1];
    #pragma unroll
    for (int j = 0; j < 4; ++j) {
        offs[tid*4+j] = base; cur[tid*4+j] = base; base += c[j];
    }
}

// Kernel 6: bucket row-ids by k (unchanged).
__global__ void fill_list(const int* __restrict__ idxi, int* __restrict__ cur,
                          int* __restrict__ list) {
    int n = blockIdx.x * 256 + threadIdx.x;
    int k = idxi[n];
    int pos = atomicAdd(&cur[k], 1);
    list[pos] = n;
}

// Kernel 7: dw[k][d] via bucketed gather from xt (unchanged).
__global__ void dw_sum(const float* __restrict__ xt,
                       const int* __restrict__ counts, const int* __restrict__ offs,
                       const int* __restrict__ list, float* __restrict__ dw) {
    __shared__ float red[128];
    int k = blockIdx.x;
    int d = threadIdx.x & 127;
    int h = threadIdx.x >> 7;
    int cnt = counts[k], base = offs[k];
    float acc = 0.f;
    for (int m = h; m < cnt; m += 2) {
        int n = list[base + m];
        acc += xt[(size_t)n * ND + d];
    }
    if (h == 1) red[d] = acc;
    __syncthreads();
    if (h == 0) dw[k * ND + d] = acc + red[d];
}

// Kernel 8: cluster-size + losses (unchanged).
__global__ void cs_loss(const int* __restrict__ counts, const float* __restrict__ ch,
                        const float* __restrict__ loss, float* __restrict__ csv,
                        float* __restrict__ out) {
    __shared__ float red[256];
    int tid = threadIdx.x;
    const float DECF = (float)(1.0 - 0.99);
    float s = 0.f;
    #pragma unroll
    for (int rr = 0; rr < 4; ++rr) {
        int k = tid + rr * 256;
        float c = (float)counts[k];
        float e = ch[k];
        float hid = e - (e - c) * DECF;
        s += hid / DECF;
    }
    red[tid] = s; __syncthreads();
    for (int off = 128; off > 0; off >>= 1) {
        if (tid < off) red[tid] += red[tid + off];
        __syncthreads();
    }
    float n = red[0];
    const float KEPSF = (float)(1024.0 * 1e-5);
    #pragma unroll
    for (int rr = 0; rr < 4; ++rr) {
        int k = tid + rr * 256;
        float c = (float)counts[k];
        float e = ch[k];
        float hid = e - (e - c) * DECF;
        float a = hid / DECF;
        csv[k] = (a + 1e-5f) / (n + KEPSF) * n;
    }
    if (tid == 0) {
        float mean = loss[0] / 16777216.f;
        out[O_LC] = 0.25f * mean;
        out[O_LV] = mean;
    }
}

// Kernel 9: new_embeddings (unchanged).
__global__ void new_emb(const float* __restrict__ dw, const float* __restrict__ dwh,
                        const float* __restrict__ csv, float* __restrict__ out) {
    int kd = blockIdx.x * 256 + threadIdx.x;
    const float DECF = (float)(1.0 - 0.99);
    float e = dwh[kd];
    float hid = e - (e - dw[kd]) * DECF;
    float a = hid / DECF;
    out[O_NE + kd] = a / csv[kd >> 7];
}

extern "C" void kernel_launch(void* const* d_in, const int* in_sizes, int n_in,
                              void* d_out, int out_size, void* d_ws, size_t ws_size,
                              hipStream_t stream) {
    const float* x   = (const float*)d_in[0];
    const float* emb = (const float*)d_in[1];
    const float* dwh = (const float*)d_in[2];
    const float* ch  = (const float*)d_in[3];
    float* out = (float*)d_out;
    float* ws  = (float*)d_ws;

    float* ET   = ws + WS_ET;
    float* ssx  = ws + WS_SSX;
    float* sse  = ws + WS_SSE;
    float* dw   = ws + WS_DW;
    float* csv  = ws + WS_CS;
    int*   counts = (int*)(ws + WS_CNT);
    int*   idxi   = (int*)(ws + WS_IDX);
    float* loss   = ws + WS_LOSS;
    int*   offs   = (int*)(ws + WS_OFFS);
    int*   cur    = (int*)(ws + WS_CUR);
    int*   list   = (int*)(ws + WS_LIST);
    float* xt     = ws + WS_XT;
    unsigned short* eb1 = (unsigned short*)(ws + WS_EB);
    unsigned short* eb2 = eb1 + NK * ND;
    unsigned short* eb3 = eb2 + NK * ND;

    hipMemsetAsync(counts, 0, NK * sizeof(int), stream);
    hipMemsetAsync(loss, 0, sizeof(float), stream);

    prep_e         <<<64,   256, 0, stream>>>(emb, ET, sse, eb1, eb2, eb3);
    calc_ssx       <<<512,  256, 0, stream>>>(x, ssx);
    transpose_x    <<<4096, 256, 0, stream>>>(x, xt);
    gemm_argmin_mfma<<<1024,256, 0, stream>>>(xt, eb1, eb2, eb3, ssx, sse, out, idxi, counts, loss);
    out_write      <<<512,  256, 0, stream>>>(x, ET, idxi, out);
    scan_offs      <<<1,    256, 0, stream>>>(counts, offs, cur);
    fill_list      <<<512,  256, 0, stream>>>(idxi, cur, list);
    dw_sum         <<<1024, 256, 0, stream>>>(xt, counts, offs, list, dw);
    cs_loss        <<<1,    256, 0, stream>>>(counts, ch, loss, csv, out);
    new_emb        <<<512,  256, 0, stream>>>(dw, dwh, csv, out);
}

// Round 5
// 515.063 us; speedup vs baseline: 1.6502x; 1.6502x over previous
//
#include <hip/hip_runtime.h>

#define NB 64
#define ND 128
#define NT 2048
#define NK 1024
#define NN (NB*NT)            // 131072
#define DTSTRIDE (ND*NT)      // 262144, b-stride in x

typedef __attribute__((ext_vector_type(8))) short bf16x8;
typedef __attribute__((ext_vector_type(4))) float floatx4;

// ---- workspace layout (float index) ----
#define WS_ET    0            // 131072 floats, ET[d][k] fp32 (for out_write gather)
#define WS_SSX   131072       // 131072 floats, |x_n|^2
#define WS_SSE   262144       // 1024 floats,  |e_k|^2
#define WS_DW    263168       // 131072 floats, dw[k][d]
#define WS_CS    394240       // 1024 floats
#define WS_CNT   395264       // 1024 ints, counts
#define WS_IDX   396288       // 131072 ints, argmin indices
#define WS_LOSS  527360       // 1 float
#define WS_OFFS  527364       // 1024 ints
#define WS_CUR   528388       // 1024 ints
#define WS_LIST  529412       // 131072 ints
#define WS_XT    660736       // 16777216 floats, xt[n][d]
#define WS_EB    17437952     // 3 x 131072 ushorts: bf16 e-planes, PRE-SWIZZLED
                              // [dchunk 4][k 1024][slot 4][8] ; slot = q ^ ((k>>1)&3)

// ---- output layout ----
#define O_OUT 0
#define O_LC  16777216
#define O_LV  16777217
#define O_IDX 16777218
#define O_NE  16908290

#define GLL16(g, l) __builtin_amdgcn_global_load_lds( \
    (const __attribute__((address_space(1))) unsigned int*)(g), \
    (__attribute__((address_space(3))) unsigned int*)(l), 16, 0, 0)

// exact truncation split of fp32 into 3 bf16 (bit patterns)
__device__ inline void split1(float v, unsigned short &a, unsigned short &b,
                              unsigned short &c) {
    unsigned int u = __float_as_uint(v);
    a = (unsigned short)(u >> 16);
    float f1 = __uint_as_float(u & 0xffff0000u);
    float r = v - f1;
    unsigned int ur = __float_as_uint(r);
    b = (unsigned short)(ur >> 16);
    float f2 = __uint_as_float(ur & 0xffff0000u);
    float r2 = r - f2;
    c = (unsigned short)(__float_as_uint(r2) >> 16);
}

// pack 2 consecutive elements into one uint per plane
__device__ inline void split2(float va, float vb, unsigned int &p1,
                              unsigned int &p2, unsigned int &p3) {
    unsigned int ua = __float_as_uint(va), ub = __float_as_uint(vb);
    p1 = (ua >> 16) | (ub & 0xffff0000u);
    float fa = __uint_as_float(ua & 0xffff0000u);
    float fb = __uint_as_float(ub & 0xffff0000u);
    float ra = va - fa, rb = vb - fb;
    unsigned int ura = __float_as_uint(ra), urb = __float_as_uint(rb);
    p2 = (ura >> 16) | (urb & 0xffff0000u);
    float f2a = __uint_as_float(ura & 0xffff0000u);
    float f2b = __uint_as_float(urb & 0xffff0000u);
    float r2a = ra - f2a, r2b = rb - f2b;
    p3 = (__float_as_uint(r2a) >> 16) | (__float_as_uint(r2b) & 0xffff0000u);
}

// Kernel 1: ET fp32 [d][k], sse, bf16 e-planes pre-swizzled for LDS staging.
__global__ void prep_e(const float* __restrict__ emb, float* __restrict__ ET,
                       float* __restrict__ sse, unsigned short* __restrict__ eb1,
                       unsigned short* __restrict__ eb2, unsigned short* __restrict__ eb3) {
    int tid = threadIdx.x;
    int k   = blockIdx.x * 16 + (tid >> 4);
    int l   = tid & 15;
    float ss = 0.f;
    #pragma unroll
    for (int it = 0; it < 2; ++it) {
        int d0 = l * 4 + it * 64;
        float4 v = *(const float4*)(emb + k * ND + d0);
        ET[(d0+0)*NK + k] = v.x;
        ET[(d0+1)*NK + k] = v.y;
        ET[(d0+2)*NK + k] = v.z;
        ET[(d0+3)*NK + k] = v.w;
        ss = fmaf(v.x, v.x, ss); ss = fmaf(v.y, v.y, ss);
        ss = fmaf(v.z, v.z, ss); ss = fmaf(v.w, v.w, ss);
        int dc  = (l >> 3) + it * 2;
        int d5  = d0 & 31;                 // 0,4,...,28
        int qb  = (d5 >> 3) & 3;           // 16B block index
        int sl  = qb ^ ((k >> 1) & 3);     // swizzled slot (matches LDS read)
        int off = (dc * NK + k) * 32 + (sl << 3) + (d5 & 7);
        ushort4 a, b, c;
        split1(v.x, a.x, b.x, c.x);
        split1(v.y, a.y, b.y, c.y);
        split1(v.z, a.z, b.z, c.z);
        split1(v.w, a.w, b.w, c.w);
        *(ushort4*)(eb1 + off) = a;
        *(ushort4*)(eb2 + off) = b;
        *(ushort4*)(eb3 + off) = c;
    }
    for (int m = 1; m <= 8; m <<= 1) ss += __shfl_xor(ss, m);
    if (l == 0) sse[k] = ss;
}

// Kernel 2: |x_n|^2 (unchanged — argmin numerics stable).
__global__ void calc_ssx(const float* __restrict__ x, float* __restrict__ ssx) {
    int b = blockIdx.x >> 3;
    int t = ((blockIdx.x & 7) << 8) + threadIdx.x;
    const float* xp = x + b * DTSTRIDE + t;
    float ss = 0.f;
    #pragma unroll 8
    for (int d = 0; d < ND; ++d) { float v = xp[d * NT]; ss = fmaf(v, v, ss); }
    ssx[b * NT + t] = ss;
}

// Kernel 2b: transpose x[B][D][T] -> xt[N][D] (unchanged).
__global__ void transpose_x(const float* __restrict__ x, float* __restrict__ xt) {
    __shared__ float tile[128][33];
    int tid = threadIdx.x;
    int b   = blockIdx.x >> 6;
    int t0  = (blockIdx.x & 63) << 5;
    int tl  = tid & 31;
    int dg  = tid >> 5;
    const float* xp = x + b * DTSTRIDE + t0 + tl;
    #pragma unroll
    for (int p = 0; p < 16; ++p) {
        int d = p * 8 + dg;
        tile[d][tl] = xp[d * NT];
    }
    __syncthreads();
    float* xtp = xt + (size_t)(b * NT + t0) * ND;
    #pragma unroll
    for (int c = 0; c < 4; ++c) {
        int d = c * 32 + (tid & 31);
        #pragma unroll
        for (int p = 0; p < 4; ++p) {
            int tr = p * 8 + (tid >> 5);
            xtp[tr * ND + d] = tile[d][tr];
        }
    }
}

// stage the (kt,dc) e-slice for iteration `it` into LDS buffer it&1 (async).
__device__ __forceinline__ void stage_eb(int it, int w, int lane,
        unsigned short* smem, const unsigned short* eb1,
        const unsigned short* eb2, const unsigned short* eb3) {
    int goff = ((it & 3) << 15) + ((it >> 2) << 12);   // dc*32768 + kt*4096 ushorts
    int bufo = (it & 1) * 12288;
    #pragma unroll
    for (int i = 0; i < 2; ++i) {
        int ch = (w << 1) + i;                          // 1KB chunk 0..7
        int so = goff + (ch << 9) + (lane << 3);        // per-lane 16B
        GLL16(eb1 + so, &smem[bufo + 0*4096 + (ch << 9)]);
        GLL16(eb2 + so, &smem[bufo + 1*4096 + (ch << 9)]);
        GLL16(eb3 + so, &smem[bufo + 2*4096 + (ch << 9)]);
    }
}

// Kernel 3: MFMA distance GEMM: A in registers, B double-buffered in LDS.
__launch_bounds__(256, 2)
__global__ void gemm_argmin_mfma(const float* __restrict__ xt,
                                 const unsigned short* __restrict__ eb1,
                                 const unsigned short* __restrict__ eb2,
                                 const unsigned short* __restrict__ eb3,
                                 const float* __restrict__ ssx, const float* __restrict__ sse,
                                 float* __restrict__ out, int* __restrict__ idxi,
                                 int* __restrict__ counts, float* __restrict__ loss) {
    __shared__ unsigned short smem[24576];   // 2 bufs x 3 planes x 4096 ushorts = 48 KB
    int tid = threadIdx.x;
    int b   = blockIdx.x >> 4;
    int t0  = (blockIdx.x & 15) << 7;
    int n0  = b * NT + t0;

    int lane = tid & 63;
    int w    = tid >> 6;          // wave id: rows [w*32, w*32+32)
    int c    = lane & 15;
    int q    = lane >> 4;
    int slot = q ^ ((c >> 1) & 3);

    // prologue: kick off B staging for iteration 0 ASAP
    stage_eb(0, w, lane, smem, eb1, eb2, eb3);

    // ---- load + split A fragments once: af[dc][i][plane] ----
    bf16x8 af[4][2][3];
    #pragma unroll
    for (int dc = 0; dc < 4; ++dc) {
        #pragma unroll
        for (int i = 0; i < 2; ++i) {
            const float* xp = xt + (size_t)(n0 + w*32 + i*16 + c) * ND + dc*32 + q*8;
            float4 v0 = *(const float4*)(xp + 0);
            float4 v1 = *(const float4*)(xp + 4);
            unsigned int p1[4], p2[4], p3[4];
            split2(v0.x, v0.y, p1[0], p2[0], p3[0]);
            split2(v0.z, v0.w, p1[1], p2[1], p3[1]);
            split2(v1.x, v1.y, p1[2], p2[2], p3[2]);
            split2(v1.z, v1.w, p1[3], p2[3], p3[3]);
            uint4 u;
            u = make_uint4(p1[0], p1[1], p1[2], p1[3]); af[dc][i][0] = *(bf16x8*)&u;
            u = make_uint4(p2[0], p2[1], p2[2], p2[3]); af[dc][i][1] = *(bf16x8*)&u;
            u = make_uint4(p3[0], p3[1], p3[2], p3[3]); af[dc][i][2] = *(bf16x8*)&u;
        }
    }

    float ssxv[8];
    #pragma unroll
    for (int i = 0; i < 2; ++i)
        #pragma unroll
        for (int rr = 0; rr < 4; ++rr)
            ssxv[i*4+rr] = ssx[n0 + w*32 + i*16 + q*4 + rr];

    float bestD[8]; int bestK[8];
    #pragma unroll
    for (int i = 0; i < 8; ++i) { bestD[i] = 3.4e38f; bestK[i] = 0; }

    floatx4 acc[2][8];
    float ssev[8];

    for (int it = 0; it < 32; ++it) {
        int kt = it >> 2, dc = it & 3, bufo = (it & 1) * 12288;
        // barrier: joins compute(it-1) (frees buffer (it+1)&1) and makes
        // loads(it) — in flight since before compute(it-1) — visible.
        __syncthreads();
        if (it + 1 < 32)
            stage_eb(it + 1, w, lane, smem, eb1, eb2, eb3);

        if (dc == 0) {
            #pragma unroll
            for (int i = 0; i < 2; ++i)
                #pragma unroll
                for (int j = 0; j < 8; ++j)
                    acc[i][j] = (floatx4){0.f, 0.f, 0.f, 0.f};
            #pragma unroll
            for (int j = 0; j < 8; ++j)
                ssev[j] = sse[(kt << 7) + (j << 4) + c];
        }

        #pragma unroll
        for (int j = 0; j < 8; ++j) {
            int ro = bufo + ((j << 4) + c) * 32 + slot * 8;
            bf16x8 b1 = *(const bf16x8*)(&smem[ro + 0*4096]);
            bf16x8 b2 = *(const bf16x8*)(&smem[ro + 1*4096]);
            bf16x8 b3 = *(const bf16x8*)(&smem[ro + 2*4096]);
            #pragma unroll
            for (int i = 0; i < 2; ++i) {
                acc[i][j] = __builtin_amdgcn_mfma_f32_16x16x32_bf16(af[dc][i][0], b1, acc[i][j], 0, 0, 0);
                acc[i][j] = __builtin_amdgcn_mfma_f32_16x16x32_bf16(af[dc][i][0], b2, acc[i][j], 0, 0, 0);
                acc[i][j] = __builtin_amdgcn_mfma_f32_16x16x32_bf16(af[dc][i][1], b1, acc[i][j], 0, 0, 0);
                acc[i][j] = __builtin_amdgcn_mfma_f32_16x16x32_bf16(af[dc][i][1], b2, acc[i][j], 0, 0, 0);
                acc[i][j] = __builtin_amdgcn_mfma_f32_16x16x32_bf16(af[dc][i][0], b3, acc[i][j], 0, 0, 0);
                acc[i][j] = __builtin_amdgcn_mfma_f32_16x16x32_bf16(af[dc][i][2], b1, acc[i][j], 0, 0, 0);
            }
        }

        if (dc == 3) {
            // epilogue for kt (identical numerics to R3/R4)
            #pragma unroll
            for (int j = 0; j < 8; ++j) {
                int   kidx = (kt << 7) + (j << 4) + c;
                float se = ssev[j];
                #pragma unroll
                for (int i = 0; i < 2; ++i) {
                    #pragma unroll
                    for (int rr = 0; rr < 4; ++rr) {
                        float t1   = ssxv[i*4+rr] + se;
                        float dist = fmaf(-2.f, acc[i][j][rr], t1);
                        if (dist < bestD[i*4+rr]) { bestD[i*4+rr] = dist; bestK[i*4+rr] = kidx; }
                    }
                }
            }
        }
    }

    // cross-lane argmin over the 16 c-lanes (ties -> smaller k)
    #pragma unroll
    for (int i = 0; i < 8; ++i) {
        float d = bestD[i]; int kk = bestK[i];
        for (int m = 1; m <= 8; m <<= 1) {
            float od = __shfl_xor(d, m);
            int   ok = __shfl_xor(kk, m);
            if (od < d || (od == d && ok < kk)) { d = od; kk = ok; }
        }
        bestD[i] = d; bestK[i] = kk;
    }
    if (c == 0) {
        float ls = 0.f;
        #pragma unroll
        for (int i = 0; i < 2; ++i)
            #pragma unroll
            for (int rr = 0; rr < 4; ++rr) {
                int n = n0 + w*32 + i*16 + q*4 + rr;
                int kk = bestK[i*4+rr];
                out[O_IDX + n] = (float)kk;
                idxi[n] = kk;
                atomicAdd(&counts[kk], 1);
                ls += bestD[i*4+rr];
            }
        atomicAdd(loss, ls);
    }
}

// Kernel 4: straight-through output (unchanged).
__global__ void out_write(const float* __restrict__ x, const float* __restrict__ ET,
                          const int* __restrict__ idxi, float* __restrict__ out) {
    int b = blockIdx.x >> 3;
    int t = ((blockIdx.x & 7) << 8) + threadIdx.x;
    int k = idxi[b * NT + t];
    const float* xp = x + b * DTSTRIDE + t;
    float*       op = out + O_OUT + b * DTSTRIDE + t;
    #pragma unroll 4
    for (int d = 0; d < ND; ++d) {
        float xv = xp[d * NT];
        float q  = ET[d * NK + k];
        op[d * NT] = xv + (q - xv);
    }
}

// Kernel 5: exclusive scan of counts (unchanged).
__global__ void scan_offs(const int* __restrict__ counts, int* __restrict__ offs,
                          int* __restrict__ cur) {
    __shared__ int s[256];
    int tid = threadIdx.x;
    int c[4]; int sum = 0;
    #pragma unroll
    for (int j = 0; j < 4; ++j) { c[j] = counts[tid*4+j]; sum += c[j]; }
    s[tid] = sum; __syncthreads();
    for (int off = 1; off < 256; off <<= 1) {
        int v = (tid >= off) ? s[tid - off] : 0;
        __syncthreads();
        s[tid] += v;
        __syncthreads();
    }
    int base = (tid == 0) ? 0 : s[tid-1];
    #pragma unroll
    for (int j = 0; j < 4; ++j) {
        offs[tid*4+j] = base; cur[tid*4+j] = base; base += c[j];
    }
}

// Kernel 6: bucket row-ids by k (unchanged).
__global__ void fill_list(const int* __restrict__ idxi, int* __restrict__ cur,
                          int* __restrict__ list) {
    int n = blockIdx.x * 256 + threadIdx.x;
    int k = idxi[n];
    int pos = atomicAdd(&cur[k], 1);
    list[pos] = n;
}

// Kernel 7: dw[k][d] via bucketed gather from xt (unchanged).
__global__ void dw_sum(const float* __restrict__ xt,
                       const int* __restrict__ counts, const int* __restrict__ offs,
                       const int* __restrict__ list, float* __restrict__ dw) {
    __shared__ float red[128];
    int k = blockIdx.x;
    int d = threadIdx.x & 127;
    int h = threadIdx.x >> 7;
    int cnt = counts[k], base = offs[k];
    float acc = 0.f;
    for (int m = h; m < cnt; m += 2) {
        int n = list[base + m];
        acc += xt[(size_t)n * ND + d];
    }
    if (h == 1) red[d] = acc;
    __syncthreads();
    if (h == 0) dw[k * ND + d] = acc + red[d];
}

// Kernel 8: cluster-size + losses (unchanged).
__global__ void cs_loss(const int* __restrict__ counts, const float* __restrict__ ch,
                        const float* __restrict__ loss, float* __restrict__ csv,
                        float* __restrict__ out) {
    __shared__ float red[256];
    int tid = threadIdx.x;
    const float DECF = (float)(1.0 - 0.99);
    float s = 0.f;
    #pragma unroll
    for (int rr = 0; rr < 4; ++rr) {
        int k = tid + rr * 256;
        float c = (float)counts[k];
        float e = ch[k];
        float hid = e - (e - c) * DECF;
        s += hid / DECF;
    }
    red[tid] = s; __syncthreads();
    for (int off = 128; off > 0; off >>= 1) {
        if (tid < off) red[tid] += red[tid + off];
        __syncthreads();
    }
    float n = red[0];
    const float KEPSF = (float)(1024.0 * 1e-5);
    #pragma unroll
    for (int rr = 0; rr < 4; ++rr) {
        int k = tid + rr * 256;
        float c = (float)counts[k];
        float e = ch[k];
        float hid = e - (e - c) * DECF;
        float a = hid / DECF;
        csv[k] = (a + 1e-5f) / (n + KEPSF) * n;
    }
    if (tid == 0) {
        float mean = loss[0] / 16777216.f;
        out[O_LC] = 0.25f * mean;
        out[O_LV] = mean;
    }
}

// Kernel 9: new_embeddings (unchanged).
__global__ void new_emb(const float* __restrict__ dw, const float* __restrict__ dwh,
                        const float* __restrict__ csv, float* __restrict__ out) {
    int kd = blockIdx.x * 256 + threadIdx.x;
    const float DECF = (float)(1.0 - 0.99);
    float e = dwh[kd];
    float hid = e - (e - dw[kd]) * DECF;
    float a = hid / DECF;
    out[O_NE + kd] = a / csv[kd >> 7];
}

extern "C" void kernel_launch(void* const* d_in, const int* in_sizes, int n_in,
                              void* d_out, int out_size, void* d_ws, size_t ws_size,
                              hipStream_t stream) {
    const float* x   = (const float*)d_in[0];
    const float* emb = (const float*)d_in[1];
    const float* dwh = (const float*)d_in[2];
    const float* ch  = (const float*)d_in[3];
    float* out = (float*)d_out;
    float* ws  = (float*)d_ws;

    float* ET   = ws + WS_ET;
    float* ssx  = ws + WS_SSX;
    float* sse  = ws + WS_SSE;
    float* dw   = ws + WS_DW;
    float* csv  = ws + WS_CS;
    int*   counts = (int*)(ws + WS_CNT);
    int*   idxi   = (int*)(ws + WS_IDX);
    float* loss   = ws + WS_LOSS;
    int*   offs   = (int*)(ws + WS_OFFS);
    int*   cur    = (int*)(ws + WS_CUR);
    int*   list   = (int*)(ws + WS_LIST);
    float* xt     = ws + WS_XT;
    unsigned short* eb1 = (unsigned short*)(ws + WS_EB);
    unsigned short* eb2 = eb1 + NK * ND;
    unsigned short* eb3 = eb2 + NK * ND;

    hipMemsetAsync(counts, 0, NK * sizeof(int), stream);
    hipMemsetAsync(loss, 0, sizeof(float), stream);

    prep_e         <<<64,   256, 0, stream>>>(emb, ET, sse, eb1, eb2, eb3);
    calc_ssx       <<<512,  256, 0, stream>>>(x, ssx);
    transpose_x    <<<4096, 256, 0, stream>>>(x, xt);
    gemm_argmin_mfma<<<1024,256, 0, stream>>>(xt, eb1, eb2, eb3, ssx, sse, out, idxi, counts, loss);
    out_write      <<<512,  256, 0, stream>>>(x, ET, idxi, out);
    scan_offs      <<<1,    256, 0, stream>>>(counts, offs, cur);
    fill_list      <<<512,  256, 0, stream>>>(idxi, cur, list);
    dw_sum         <<<1024, 256, 0, stream>>>(xt, counts, offs, list, dw);
    cs_loss        <<<1,    256, 0, stream>>>(counts, ch, loss, csv, out);
    new_emb        <<<512,  256, 0, stream>>>(dw, dwh, csv, out);
}

// Round 6
// 504.434 us; speedup vs baseline: 1.6850x; 1.0211x over previous
//
#include <hip/hip_runtime.h>

#define NB 64
#define ND 128
#define NT 2048
#define NK 1024
#define NN (NB*NT)            // 131072
#define DTSTRIDE (ND*NT)      // 262144, b-stride in x

typedef __attribute__((ext_vector_type(8))) short bf16x8;
typedef __attribute__((ext_vector_type(4))) float floatx4;

// ---- workspace layout (float index) ----
#define WS_ET    0            // 131072 floats, ET[d][k] fp32 (for out_write gather)
#define WS_SSX   131072       // 131072 floats, |x_n|^2
#define WS_SSE   262144       // 1024 floats,  |e_k|^2
#define WS_DW    263168       // 131072 floats, dw[k][d]
#define WS_CS    394240       // 1024 floats
#define WS_CNT   395264       // 1024 ints, counts
#define WS_IDX   396288       // 131072 ints, argmin indices
#define WS_LOSS  527360       // 1 float
#define WS_OFFS  527364       // 1024 ints
#define WS_CUR   528388       // 1024 ints
#define WS_LIST  529412       // 131072 ints
#define WS_XT    660736       // 16777216 floats, xt[n][d]
#define WS_EB    17437952     // 3 x 131072 ushorts: bf16 e-planes, PRE-SWIZZLED
                              // [dchunk 4][k 1024][slot 4][8] ; slot = q ^ ((k>>1)&3)

// ---- output layout ----
#define O_OUT 0
#define O_LC  16777216
#define O_LV  16777217
#define O_IDX 16777218
#define O_NE  16908290

#define GLL16(g, l) __builtin_amdgcn_global_load_lds( \
    (const __attribute__((address_space(1))) unsigned int*)(g), \
    (__attribute__((address_space(3))) unsigned int*)(l), 16, 0, 0)

// exact truncation split of fp32 into 3 bf16 (bit patterns)
__device__ inline void split1(float v, unsigned short &a, unsigned short &b,
                              unsigned short &c) {
    unsigned int u = __float_as_uint(v);
    a = (unsigned short)(u >> 16);
    float f1 = __uint_as_float(u & 0xffff0000u);
    float r = v - f1;
    unsigned int ur = __float_as_uint(r);
    b = (unsigned short)(ur >> 16);
    float f2 = __uint_as_float(ur & 0xffff0000u);
    float r2 = r - f2;
    c = (unsigned short)(__float_as_uint(r2) >> 16);
}

// pack 2 consecutive elements into one uint per plane
__device__ inline void split2(float va, float vb, unsigned int &p1,
                              unsigned int &p2, unsigned int &p3) {
    unsigned int ua = __float_as_uint(va), ub = __float_as_uint(vb);
    p1 = (ua >> 16) | (ub & 0xffff0000u);
    float fa = __uint_as_float(ua & 0xffff0000u);
    float fb = __uint_as_float(ub & 0xffff0000u);
    float ra = va - fa, rb = vb - fb;
    unsigned int ura = __float_as_uint(ra), urb = __float_as_uint(rb);
    p2 = (ura >> 16) | (urb & 0xffff0000u);
    float f2a = __uint_as_float(ura & 0xffff0000u);
    float f2b = __uint_as_float(urb & 0xffff0000u);
    float r2a = ra - f2a, r2b = rb - f2b;
    p3 = (__float_as_uint(r2a) >> 16) | (__float_as_uint(r2b) & 0xffff0000u);
}

// Kernel 1: ET fp32 [d][k], sse, bf16 e-planes pre-swizzled for LDS staging.
__global__ void prep_e(const float* __restrict__ emb, float* __restrict__ ET,
                       float* __restrict__ sse, unsigned short* __restrict__ eb1,
                       unsigned short* __restrict__ eb2, unsigned short* __restrict__ eb3) {
    int tid = threadIdx.x;
    int k   = blockIdx.x * 16 + (tid >> 4);
    int l   = tid & 15;
    float ss = 0.f;
    #pragma unroll
    for (int it = 0; it < 2; ++it) {
        int d0 = l * 4 + it * 64;
        float4 v = *(const float4*)(emb + k * ND + d0);
        ET[(d0+0)*NK + k] = v.x;
        ET[(d0+1)*NK + k] = v.y;
        ET[(d0+2)*NK + k] = v.z;
        ET[(d0+3)*NK + k] = v.w;
        ss = fmaf(v.x, v.x, ss); ss = fmaf(v.y, v.y, ss);
        ss = fmaf(v.z, v.z, ss); ss = fmaf(v.w, v.w, ss);
        int dc  = (l >> 3) + it * 2;
        int d5  = d0 & 31;                 // 0,4,...,28
        int qb  = (d5 >> 3) & 3;           // 16B block index
        int sl  = qb ^ ((k >> 1) & 3);     // swizzled slot (matches LDS read)
        int off = (dc * NK + k) * 32 + (sl << 3) + (d5 & 7);
        ushort4 a, b, c;
        split1(v.x, a.x, b.x, c.x);
        split1(v.y, a.y, b.y, c.y);
        split1(v.z, a.z, b.z, c.z);
        split1(v.w, a.w, b.w, c.w);
        *(ushort4*)(eb1 + off) = a;
        *(ushort4*)(eb2 + off) = b;
        *(ushort4*)(eb3 + off) = c;
    }
    for (int m = 1; m <= 8; m <<= 1) ss += __shfl_xor(ss, m);
    if (l == 0) sse[k] = ss;
}

// Kernel 2: |x_n|^2 (unchanged — argmin numerics stable).
__global__ void calc_ssx(const float* __restrict__ x, float* __restrict__ ssx) {
    int b = blockIdx.x >> 3;
    int t = ((blockIdx.x & 7) << 8) + threadIdx.x;
    const float* xp = x + b * DTSTRIDE + t;
    float ss = 0.f;
    #pragma unroll 8
    for (int d = 0; d < ND; ++d) { float v = xp[d * NT]; ss = fmaf(v, v, ss); }
    ssx[b * NT + t] = ss;
}

// Kernel 2b: transpose x[B][D][T] -> xt[N][D] (unchanged).
__global__ void transpose_x(const float* __restrict__ x, float* __restrict__ xt) {
    __shared__ float tile[128][33];
    int tid = threadIdx.x;
    int b   = blockIdx.x >> 6;
    int t0  = (blockIdx.x & 63) << 5;
    int tl  = tid & 31;
    int dg  = tid >> 5;
    const float* xp = x + b * DTSTRIDE + t0 + tl;
    #pragma unroll
    for (int p = 0; p < 16; ++p) {
        int d = p * 8 + dg;
        tile[d][tl] = xp[d * NT];
    }
    __syncthreads();
    float* xtp = xt + (size_t)(b * NT + t0) * ND;
    #pragma unroll
    for (int c = 0; c < 4; ++c) {
        int d = c * 32 + (tid & 31);
        #pragma unroll
        for (int p = 0; p < 4; ++p) {
            int tr = p * 8 + (tid >> 5);
            xtp[tr * ND + d] = tile[d][tr];
        }
    }
}

// stage the (ktp,dcp) e-slice into LDS buffer `par` (async). dcp/par are
// compile-time after unrolling; ktp may be dynamic.
__device__ __forceinline__ void stage_eb(int ktp, int dcp, int par, int w, int lane,
        unsigned short* smem, const unsigned short* eb1,
        const unsigned short* eb2, const unsigned short* eb3) {
    int goff = (dcp << 15) + (ktp << 12);   // dc*32768 + kt*4096 ushorts
    int bufo = par * 12288;
    #pragma unroll
    for (int i = 0; i < 2; ++i) {
        int ch = (w << 1) + i;                          // 1KB chunk 0..7
        int so = goff + (ch << 9) + (lane << 3);        // per-lane 16B
        GLL16(eb1 + so, &smem[bufo + 0*4096 + (ch << 9)]);
        GLL16(eb2 + so, &smem[bufo + 1*4096 + (ch << 9)]);
        GLL16(eb3 + so, &smem[bufo + 2*4096 + (ch << 9)]);
    }
}

// Kernel 3: MFMA distance GEMM: A in registers (static indexing — dc loop fully
// unrolled so af[] never spills), B double-buffered in LDS via global_load_lds.
__launch_bounds__(256, 2)
__global__ void gemm_argmin_mfma(const float* __restrict__ xt,
                                 const unsigned short* __restrict__ eb1,
                                 const unsigned short* __restrict__ eb2,
                                 const unsigned short* __restrict__ eb3,
                                 const float* __restrict__ ssx, const float* __restrict__ sse,
                                 float* __restrict__ out, int* __restrict__ idxi,
                                 int* __restrict__ counts, float* __restrict__ loss) {
    __shared__ unsigned short smem[24576];   // 2 bufs x 3 planes x 4096 ushorts = 48 KB
    int tid = threadIdx.x;
    int b   = blockIdx.x >> 4;
    int t0  = (blockIdx.x & 15) << 7;
    int n0  = b * NT + t0;

    int lane = tid & 63;
    int w    = tid >> 6;          // wave id: rows [w*32, w*32+32)
    int c    = lane & 15;
    int q    = lane >> 4;
    int slot = q ^ ((c >> 1) & 3);

    // prologue: kick off B staging for (kt=0, dc=0) into buffer 0 ASAP
    stage_eb(0, 0, 0, w, lane, smem, eb1, eb2, eb3);

    // ---- load + split A fragments once: af[dc][i][plane] (static indexing) ----
    bf16x8 af[4][2][3];
    #pragma unroll
    for (int dc = 0; dc < 4; ++dc) {
        #pragma unroll
        for (int i = 0; i < 2; ++i) {
            const float* xp = xt + (size_t)(n0 + w*32 + i*16 + c) * ND + dc*32 + q*8;
            float4 v0 = *(const float4*)(xp + 0);
            float4 v1 = *(const float4*)(xp + 4);
            unsigned int p1[4], p2[4], p3[4];
            split2(v0.x, v0.y, p1[0], p2[0], p3[0]);
            split2(v0.z, v0.w, p1[1], p2[1], p3[1]);
            split2(v1.x, v1.y, p1[2], p2[2], p3[2]);
            split2(v1.z, v1.w, p1[3], p2[3], p3[3]);
            uint4 u;
            u = make_uint4(p1[0], p1[1], p1[2], p1[3]); af[dc][i][0] = *(bf16x8*)&u;
            u = make_uint4(p2[0], p2[1], p2[2], p2[3]); af[dc][i][1] = *(bf16x8*)&u;
            u = make_uint4(p3[0], p3[1], p3[2], p3[3]); af[dc][i][2] = *(bf16x8*)&u;
        }
    }

    float ssxv[8];
    #pragma unroll
    for (int i = 0; i < 2; ++i)
        #pragma unroll
        for (int rr = 0; rr < 4; ++rr)
            ssxv[i*4+rr] = ssx[n0 + w*32 + i*16 + q*4 + rr];

    float bestD[8]; int bestK[8];
    #pragma unroll
    for (int i = 0; i < 8; ++i) { bestD[i] = 3.4e38f; bestK[i] = 0; }

    floatx4 acc[2][8];
    float ssev[8];

    for (int kt = 0; kt < 8; ++kt) {
        #pragma unroll
        for (int i = 0; i < 2; ++i)
            #pragma unroll
            for (int j = 0; j < 8; ++j)
                acc[i][j] = (floatx4){0.f, 0.f, 0.f, 0.f};
        #pragma unroll
        for (int j = 0; j < 8; ++j)
            ssev[j] = sse[(kt << 7) + (j << 4) + c];

        #pragma unroll
        for (int dc = 0; dc < 4; ++dc) {
            int bufo = (dc & 1) * 12288;            // parity of it = 4*kt+dc
            // barrier: joins compute(it-1) (frees buffer (it+1)&1) and makes
            // loads(it) — in flight since before compute(it-1) — visible.
            __syncthreads();
            if (dc < 3) {
                stage_eb(kt, dc + 1, (dc + 1) & 1, w, lane, smem, eb1, eb2, eb3);
            } else if (kt < 7) {
                stage_eb(kt + 1, 0, 0, w, lane, smem, eb1, eb2, eb3);
            }

            #pragma unroll
            for (int j = 0; j < 8; ++j) {
                int ro = bufo + ((j << 4) + c) * 32 + slot * 8;
                bf16x8 b1 = *(const bf16x8*)(&smem[ro + 0*4096]);
                bf16x8 b2 = *(const bf16x8*)(&smem[ro + 1*4096]);
                bf16x8 b3 = *(const bf16x8*)(&smem[ro + 2*4096]);
                #pragma unroll
                for (int i = 0; i < 2; ++i) {
                    acc[i][j] = __builtin_amdgcn_mfma_f32_16x16x32_bf16(af[dc][i][0], b1, acc[i][j], 0, 0, 0);
                    acc[i][j] = __builtin_amdgcn_mfma_f32_16x16x32_bf16(af[dc][i][0], b2, acc[i][j], 0, 0, 0);
                    acc[i][j] = __builtin_amdgcn_mfma_f32_16x16x32_bf16(af[dc][i][1], b1, acc[i][j], 0, 0, 0);
                    acc[i][j] = __builtin_amdgcn_mfma_f32_16x16x32_bf16(af[dc][i][1], b2, acc[i][j], 0, 0, 0);
                    acc[i][j] = __builtin_amdgcn_mfma_f32_16x16x32_bf16(af[dc][i][0], b3, acc[i][j], 0, 0, 0);
                    acc[i][j] = __builtin_amdgcn_mfma_f32_16x16x32_bf16(af[dc][i][2], b1, acc[i][j], 0, 0, 0);
                }
            }
        }

        // epilogue for kt (identical numerics to R3/R4/R5)
        #pragma unroll
        for (int j = 0; j < 8; ++j) {
            int   kidx = (kt << 7) + (j << 4) + c;
            float se = ssev[j];
            #pragma unroll
            for (int i = 0; i < 2; ++i) {
                #pragma unroll
                for (int rr = 0; rr < 4; ++rr) {
                    float t1   = ssxv[i*4+rr] + se;
                    float dist = fmaf(-2.f, acc[i][j][rr], t1);
                    if (dist < bestD[i*4+rr]) { bestD[i*4+rr] = dist; bestK[i*4+rr] = kidx; }
                }
            }
        }
    }

    // cross-lane argmin over the 16 c-lanes (ties -> smaller k)
    #pragma unroll
    for (int i = 0; i < 8; ++i) {
        float d = bestD[i]; int kk = bestK[i];
        for (int m = 1; m <= 8; m <<= 1) {
            float od = __shfl_xor(d, m);
            int   ok = __shfl_xor(kk, m);
            if (od < d || (od == d && ok < kk)) { d = od; kk = ok; }
        }
        bestD[i] = d; bestK[i] = kk;
    }
    if (c == 0) {
        float ls = 0.f;
        #pragma unroll
        for (int i = 0; i < 2; ++i)
            #pragma unroll
            for (int rr = 0; rr < 4; ++rr) {
                int n = n0 + w*32 + i*16 + q*4 + rr;
                int kk = bestK[i*4+rr];
                out[O_IDX + n] = (float)kk;
                idxi[n] = kk;
                atomicAdd(&counts[kk], 1);
                ls += bestD[i*4+rr];
            }
        atomicAdd(loss, ls);
    }
}

// Kernel 4: straight-through output (unchanged).
__global__ void out_write(const float* __restrict__ x, const float* __restrict__ ET,
                          const int* __restrict__ idxi, float* __restrict__ out) {
    int b = blockIdx.x >> 3;
    int t = ((blockIdx.x & 7) << 8) + threadIdx.x;
    int k = idxi[b * NT + t];
    const float* xp = x + b * DTSTRIDE + t;
    float*       op = out + O_OUT + b * DTSTRIDE + t;
    #pragma unroll 4
    for (int d = 0; d < ND; ++d) {
        float xv = xp[d * NT];
        float q  = ET[d * NK + k];
        op[d * NT] = xv + (q - xv);
    }
}

// Kernel 5: exclusive scan of counts (unchanged).
__global__ void scan_offs(const int* __restrict__ counts, int* __restrict__ offs,
                          int* __restrict__ cur) {
    __shared__ int s[256];
    int tid = threadIdx.x;
    int c[4]; int sum = 0;
    #pragma unroll
    for (int j = 0; j < 4; ++j) { c[j] = counts[tid*4+j]; sum += c[j]; }
    s[tid] = sum; __syncthreads();
    for (int off = 1; off < 256; off <<= 1) {
        int v = (tid >= off) ? s[tid - off] : 0;
        __syncthreads();
        s[tid] += v;
        __syncthreads();
    }
    int base = (tid == 0) ? 0 : s[tid-1];
    #pragma unroll
    for (int j = 0; j < 4; ++j) {
        offs[tid*4+j] = base; cur[tid*4+j] = base; base += c[j];
    }
}

// Kernel 6: bucket row-ids by k (unchanged).
__global__ void fill_list(const int* __restrict__ idxi, int* __restrict__ cur,
                          int* __restrict__ list) {
    int n = blockIdx.x * 256 + threadIdx.x;
    int k = idxi[n];
    int pos = atomicAdd(&cur[k], 1);
    list[pos] = n;
}

// Kernel 7: dw[k][d] via bucketed gather from xt (unchanged).
__global__ void dw_sum(const float* __restrict__ xt,
                       const int* __restrict__ counts, const int* __restrict__ offs,
                       const int* __restrict__ list, float* __restrict__ dw) {
    __shared__ float red[128];
    int k = blockIdx.x;
    int d = threadIdx.x & 127;
    int h = threadIdx.x >> 7;
    int cnt = counts[k], base = offs[k];
    float acc = 0.f;
    for (int m = h; m < cnt; m += 2) {
        int n = list[base + m];
        acc += xt[(size_t)n * ND + d];
    }
    if (h == 1) red[d] = acc;
    __syncthreads();
    if (h == 0) dw[k * ND + d] = acc + red[d];
}

// Kernel 8: cluster-size + losses (unchanged).
__global__ void cs_loss(const int* __restrict__ counts, const float* __restrict__ ch,
                        const float* __restrict__ loss, float* __restrict__ csv,
                        float* __restrict__ out) {
    __shared__ float red[256];
    int tid = threadIdx.x;
    const float DECF = (float)(1.0 - 0.99);
    float s = 0.f;
    #pragma unroll
    for (int rr = 0; rr < 4; ++rr) {
        int k = tid + rr * 256;
        float c = (float)counts[k];
        float e = ch[k];
        float hid = e - (e - c) * DECF;
        s += hid / DECF;
    }
    red[tid] = s; __syncthreads();
    for (int off = 128; off > 0; off >>= 1) {
        if (tid < off) red[tid] += red[tid + off];
        __syncthreads();
    }
    float n = red[0];
    const float KEPSF = (float)(1024.0 * 1e-5);
    #pragma unroll
    for (int rr = 0; rr < 4; ++rr) {
        int k = tid + rr * 256;
        float c = (float)counts[k];
        float e = ch[k];
        float hid = e - (e - c) * DECF;
        float a = hid / DECF;
        csv[k] = (a + 1e-5f) / (n + KEPSF) * n;
    }
    if (tid == 0) {
        float mean = loss[0] / 16777216.f;
        out[O_LC] = 0.25f * mean;
        out[O_LV] = mean;
    }
}

// Kernel 9: new_embeddings (unchanged).
__global__ void new_emb(const float* __restrict__ dw, const float* __restrict__ dwh,
                        const float* __restrict__ csv, float* __restrict__ out) {
    int kd = blockIdx.x * 256 + threadIdx.x;
    const float DECF = (float)(1.0 - 0.99);
    float e = dwh[kd];
    float hid = e - (e - dw[kd]) * DECF;
    float a = hid / DECF;
    out[O_NE + kd] = a / csv[kd >> 7];
}

extern "C" void kernel_launch(void* const* d_in, const int* in_sizes, int n_in,
                              void* d_out, int out_size, void* d_ws, size_t ws_size,
                              hipStream_t stream) {
    const float* x   = (const float*)d_in[0];
    const float* emb = (const float*)d_in[1];
    const float* dwh = (const float*)d_in[2];
    const float* ch  = (const float*)d_in[3];
    float* out = (float*)d_out;
    float* ws  = (float*)d_ws;

    float* ET   = ws + WS_ET;
    float* ssx  = ws + WS_SSX;
    float* sse  = ws + WS_SSE;
    float* dw   = ws + WS_DW;
    float* csv  = ws + WS_CS;
    int*   counts = (int*)(ws + WS_CNT);
    int*   idxi   = (int*)(ws + WS_IDX);
    float* loss   = ws + WS_LOSS;
    int*   offs   = (int*)(ws + WS_OFFS);
    int*   cur    = (int*)(ws + WS_CUR);
    int*   list   = (int*)(ws + WS_LIST);
    float* xt     = ws + WS_XT;
    unsigned short* eb1 = (unsigned short*)(ws + WS_EB);
    unsigned short* eb2 = eb1 + NK * ND;
    unsigned short* eb3 = eb2 + NK * ND;

    hipMemsetAsync(counts, 0, NK * sizeof(int), stream);
    hipMemsetAsync(loss, 0, sizeof(float), stream);

    prep_e         <<<64,   256, 0, stream>>>(emb, ET, sse, eb1, eb2, eb3);
    calc_ssx       <<<512,  256, 0, stream>>>(x, ssx);
    transpose_x    <<<4096, 256, 0, stream>>>(x, xt);
    gemm_argmin_mfma<<<1024,256, 0, stream>>>(xt, eb1, eb2, eb3, ssx, sse, out, idxi, counts, loss);
    out_write      <<<512,  256, 0, stream>>>(x, ET, idxi, out);
    scan_offs      <<<1,    256, 0, stream>>>(counts, offs, cur);
    fill_list      <<<512,  256, 0, stream>>>(idxi, cur, list);
    dw_sum         <<<1024, 256, 0, stream>>>(xt, counts, offs, list, dw);
    cs_loss        <<<1,    256, 0, stream>>>(counts, ch, loss, csv, out);
    new_emb        <<<512,  256, 0, stream>>>(dw, dwh, csv, out);
}